// Round 8
// baseline (1182.079 us; speedup 1.0000x reference)
//
#include <hip/hip_runtime.h>

#define NVEL  400
#define PMLW  20
#define NSIDE 440
#define BATCH 4
#define NT    100
#define NREC  100

#define TS 55               // tile side; 8x8 tiles x 4 batches = 256 blocks
#define GT 8
#define WP 68               // wf pitch (16B-aligned quads; cols 0..62 used)
#define WROWS 63            // wf rows: cell -4..58
#define WHALF (WROWS*WP)    // 4284
#define PYP 56              // psiy pitch: rows 0..58 = cell rows -2..56, cols x 0..54 (+pad)
#define PXP 60              // psix pitch: rows y 0..54, cols j 0..58 (+pad), j = x+2
#define C1f (1.0f/48.0f)
#define C2f (1.0f/192.0f)
#define NTH 1024
#define NSTRIP 880          // 4 edges x 4 x 55
#define SPITCH (256*NSTRIP) // strips per parity

typedef float f4 __attribute__((ext_vector_type(4)));
#define F4(x) (*(f4*)&(x))
#define WIDX(y,x) (((y)+4)*WP + ((x)+4))

__global__ __launch_bounds__(NTH, 1) void kWave(
    const float* __restrict__ v, const float* __restrict__ amp,
    const int* __restrict__ sloc, const int* __restrict__ rloc,
    float* __restrict__ out, int* __restrict__ flags, float* __restrict__ strips)
{
    __shared__ __align__(16) float sWF[2*WHALF];
    __shared__ __align__(16) float sPY[59*PYP];
    __shared__ __align__(16) float sPX[TS*PXP];
    __shared__ float pa_y[63], pb_y[63], pa_x[63], pb_x[63];
    __shared__ float sAmp[NT];
    __shared__ int expCnt, initCnt;

    const int tid = threadIdx.x;
    const int bid = blockIdx.x;
    const int b   = bid >> 6;
    const int tl  = bid & 63;
    const int tyi = tl >> 3, txi = tl & 7;
    const int by0 = tyi*TS, bx0 = txi*TS;
    const int nbN = (tyi > 0)    ? bid - GT : -1;
    const int nbS = (tyi < GT-1) ? bid + GT : -1;
    const int nbW = (txi > 0)    ? bid - 1  : -1;
    const int nbE = (txi < GT-1) ? bid + 1  : -1;

    // ---- zero LDS state ----
    for (int i = tid; i < 2*WHALF; i += NTH) sWF[i] = 0.f;
    for (int i = tid; i < 59*PYP; i += NTH) sPY[i] = 0.f;
    for (int i = tid; i < TS*PXP; i += NTH) sPX[i] = 0.f;
    if (tid == 0) initCnt = 0;
    if (tid < 63) {
        const float smax = (float)(3.0*2600.0*6.907755278982137/160.0);
        float gy = (float)(by0 + tid - 4);
        float dy = fmaxf(fminf(fmaxf((20.f-gy)/20.f,0.f),1.f),
                         fminf(fmaxf((gy-419.f)/20.f,0.f),1.f));
        float bby = expf(-smax*dy*dy*0.0008f);
        pb_y[tid] = bby; pa_y[tid] = bby - 1.f;
        float gx = (float)(bx0 + tid - 4);
        float dx = fmaxf(fminf(fmaxf((20.f-gx)/20.f,0.f),1.f),
                         fminf(fmaxf((gx-419.f)/20.f,0.f),1.f));
        float bbx = expf(-smax*dx*dx*0.0008f);
        pb_x[tid] = bbx; pa_x[tid] = bbx - 1.f;
    }
    if (tid < NT) sAmp[tid] = amp[b*NT + tid];
    __syncthreads();

    // ================= loop-invariant per-thread descriptors =================
    // psiy slot: storage row ri=tid/14 (cell row ri-2), quad x = (tid%14)*4
    const bool pyOn = (tid < 826);
    const int  pyRi = tid/14, pyQx = (tid - 14*pyRi)*4;
    const bool pyCore = pyOn && (pyRi >= 4 && pyRi <= 54);
    const bool pyRim  = pyOn && !(pyRi >= 4 && pyRi <= 54);
    const int  pyWf  = pyRi*WP + (pyQx+4);
    const int  pyIdx = pyRi*PYP + pyQx;
    float pyPa = 0.f, pyPb = 0.f;
    if (pyOn) { int g = by0 + pyRi - 2;
        if (g >= 0 && g < NSIDE) { pyPa = pa_y[pyRi+2]; pyPb = pb_y[pyRi+2]; } }

    // psix slot: row y=tid/15, quad j = (tid%15)*4 (cell x = j-2+e)
    const bool pxOn = (tid < 825);
    const int  pxY = tid/15, pxQ = tid - 15*pxY, pxJ = pxQ*4;
    const bool pxCore = pxOn && (pxQ >= 1 && pxQ <= 12);
    const bool pxRim  = pxOn && !(pxQ >= 1 && pxQ <= 12);
    const int  pxWf  = (pxY+4)*WP + pxJ;
    const int  pxIdx = pxY*PXP + pxJ;
    f4 pxPa, pxPb;
    #pragma unroll
    for (int e = 0; e < 4; ++e) {
        int g = bx0 + pxJ - 2 + e;
        bool ok = pxOn && (g >= 0 && g < NSIDE);
        pxPa[e] = ok ? pa_x[pxJ+2+e] : 0.f;
        pxPb[e] = ok ? pb_x[pxJ+2+e] : 0.f;
    }

    // interior slot: row y=tid/14, quad x=(tid%14)*4
    const bool inOn = (tid < 770);
    const int  iY = tid/14, iQ = tid - 14*iY, iQx = iQ*4;
    const bool iEarly = inOn && ((iY < 4) || (iY >= 51) || (iQ == 0) || (iQ == 13));
    const bool iLate  = inOn && !((iY < 4) || (iY >= 51) || (iQ == 0) || (iQ == 13));
    const bool iTail  = (iQ == 13);
    const int  iC  = WIDX(iY, iQx);
    const int  iPy = iY*PYP + iQx;
    const int  iPx = iY*PXP + iQx;
    const float iPay = pa_y[iY+4], iPby = pb_y[iY+4];
    f4 iPax, iPbx, iV2, iSrc;
    {
        const int sgy = sloc[b*2] + PMLW, sgx = sloc[b*2+1] + PMLW;
        #pragma unroll
        for (int e = 0; e < 4; ++e) {
            iPax[e] = pa_x[iQx+e+4]; iPbx[e] = pb_x[iQx+e+4];
            int cy = min(max(by0 + iY  - PMLW, 0), NVEL-1);
            int cx = min(max(bx0 + iQx+e - PMLW, 0), NVEL-1);
            float vv = v[cy*NVEL + cx];
            iV2[e] = vv*vv*(float)(0.0008*0.0008);
            iSrc[e] = (inOn && (by0+iY == sgy) && (bx0+iQx+e == sgx)) ? iV2[e] : 0.f;
        }
    }
    f4 zY = {0.f,0.f,0.f,0.f}, zX = {0.f,0.f,0.f,0.f};

    // receivers
    int rofs = -1, rIdx = 0;
    if (tid < NREC) {
        int gry = rloc[(b*NREC+tid)*2]   + PMLW;
        int grx = rloc[(b*NREC+tid)*2+1] + PMLW;
        if (gry >= by0 && gry < by0+TS && grx >= bx0 && grx < bx0+TS) {
            rofs = (b*NREC+tid)*NT;
            rIdx = WIDX(gry-by0, grx-bx0);
        }
    }

    // import descriptors (tid<880), same strip layout as R7:
    // e0: my halo rows -4..-1 <- nb N slot1; e1: rows 55..58 <- nb S slot0;
    // e2: cols -4..-1 <- nb W slot3; e3: cols 55..58 <- nb E slot2.
    int impNb = -1, imSrc = 0, imDst = 0;
    if (tid < NSTRIP) {
        int e = tid/220, j = tid - e*220;
        if (e == 0)      { int r=j/55, c=j-55*r; impNb=nbN; imSrc=1*220+j; imDst=WIDX(r-4,c); }
        else if (e == 1) { int r=j/55, c=j-55*r; impNb=nbS; imSrc=0*220+j; imDst=WIDX(55+r,c); }
        else if (e == 2) { int r=j&3,  c=j>>2;   impNb=nbW; imSrc=3*220+j; imDst=WIDX(c,r-4); }
        else             { int r=j&3,  c=j>>2;   impNb=nbE; imSrc=2*220+j; imDst=WIDX(c,55+r); }
        if (impNb >= 0) imSrc += impNb*NSTRIP;
    }

    // export: free threads = not late-interior; 460 of them, 2 slots each
    const bool isFree = !iLate;
    unsigned long long fb = __ballot(isFree ? 1 : 0);
    const bool iFirstFree = isFree && ((tid & 63) == (__ffsll((long long)fb) - 1));
    int es0 = -1, eg0 = 0, es1 = -1, eg1 = 0;
    {
        int er = -1;
        if (isFree) er = atomicAdd(&initCnt, 1);
        #pragma unroll
        for (int s = 0; s < 2; ++s) {
            int i = er + 460*s;
            if (er >= 0 && i < NSTRIP) {
                int e = i/220, j = i - e*220, src;
                if (e == 0)      { int r=j/55, c=j-55*r; src = WIDX(r,c); }
                else if (e == 1) { int r=j/55, c=j-55*r; src = WIDX(51+r,c); }
                else if (e == 2) { int r=j&3,  c=j>>2;   src = WIDX(c,r); }
                else             { int r=j&3,  c=j>>2;   src = WIDX(c,51+r); }
                if (s == 0) { es0 = src; eg0 = bid*NSTRIP + i; }
                else        { es1 = src; eg1 = bid*NSTRIP + i; }
            }
        }
    }
    __syncthreads();

    int co = 0;   // cur = sWF+co, nxt = sWF+(co^WHALF)

#define PSIY_BODY { \
    f4 r0 = F4(sWF[co+pyWf]);      f4 r1 = F4(sWF[co+pyWf+WP]); \
    f4 r3 = F4(sWF[co+pyWf+3*WP]); f4 r4 = F4(sWF[co+pyWf+4*WP]); \
    f4 po = F4(sPY[pyIdx]); f4 nv; \
    _Pragma("unroll") for (int e = 0; e < 4; ++e) { \
        float d1 = (r0[e] - r4[e] + 8.f*(r3[e] - r1[e]))*C1f; \
        nv[e] = pyPb*po[e] + pyPa*d1; } \
    F4(sPY[pyIdx]) = nv; }

#define PSIX_BODY { \
    f4 L = F4(sWF[co+pxWf]); f4 R = F4(sWF[co+pxWf+4]); \
    f4 po = F4(sPX[pxIdx]); f4 nv; \
    float w8[8] = {L.x,L.y,L.z,L.w,R.x,R.y,R.z,R.w}; \
    _Pragma("unroll") for (int e = 0; e < 4; ++e) { \
        float d1 = (w8[e] - w8[e+4] + 8.f*(w8[e+3] - w8[e+1]))*C1f; \
        nv[e] = pxPb[e]*po[e] + pxPa[e]*d1; } \
    F4(sPX[pxIdx]) = nv; }

#define INTERIOR_BODY { \
    int cn = co ^ WHALF; \
    f4 Cc  = F4(sWF[co+iC]); \
    f4 ym2 = F4(sWF[co+iC-2*WP]), ym1 = F4(sWF[co+iC-WP]); \
    f4 yp1 = F4(sWF[co+iC+WP]),  yp2 = F4(sWF[co+iC+2*WP]); \
    f4 xl  = F4(sWF[co+iC-4]),   xr  = F4(sWF[co+iC+4]); \
    f4 p0 = F4(sPY[iPy]),        p1 = F4(sPY[iPy+PYP]); \
    f4 p3 = F4(sPY[iPy+3*PYP]),  p4 = F4(sPY[iPy+4*PYP]); \
    f4 pl = F4(sPX[iPx]),        pr = F4(sPX[iPx+4]); \
    f4 n4 = F4(sWF[cn+iC]); \
    float xw[12] = {xl.x,xl.y,xl.z,xl.w,Cc.x,Cc.y,Cc.z,Cc.w,xr.x,xr.y,xr.z,xr.w}; \
    float pw[8]  = {pl.x,pl.y,pl.z,pl.w,pr.x,pr.y,pr.z,pr.w}; \
    float ampT = sAmp[t]; f4 w4; \
    _Pragma("unroll") for (int e = 0; e < 4; ++e) { \
        float d2y = (-(ym2[e]+yp2[e]) + 16.f*(ym1[e]+yp1[e]) - 30.f*Cc[e])*C2f \
                  + (p0[e] - p4[e] + 8.f*(p3[e] - p1[e]))*C1f; \
        float d2x = (-(xw[2+e]+xw[6+e]) + 16.f*(xw[3+e]+xw[5+e]) - 30.f*xw[4+e])*C2f \
                  + (pw[e] - pw[e+4] + 8.f*(pw[e+3] - pw[e+1]))*C1f; \
        float zy = iPby*zY[e] + iPay*d2y; \
        float zx = iPbx[e]*zX[e] + iPax[e]*d2x; \
        zY[e] = zy; zX[e] = zx; \
        w4[e] = iV2[e]*(d2y + zy + d2x + zx) + 2.f*Cc[e] - n4[e] + iSrc[e]*ampT; } \
    if (!iTail) F4(sWF[cn+iC]) = w4; \
    else { sWF[cn+iC] = w4.x; sWF[cn+iC+1] = w4.y; sWF[cn+iC+2] = w4.z; } }

    for (int t = 0; t < NT; ++t) {
        // ---- A: reset counter; poll flag; issue strip load ----
        if (tid == 0) expCnt = 0;
        float hval = 0.f;
        if (t > 0 && impNb >= 0) {
            int spin = 0;
            while (__hip_atomic_load(&flags[impNb], __ATOMIC_RELAXED,
                                     __HIP_MEMORY_SCOPE_AGENT) < t
                   && spin < 2000000) { __builtin_amdgcn_s_sleep(1); ++spin; }
            hval = __hip_atomic_load(&strips[((t-1)&1)*SPITCH + imSrc],
                                     __ATOMIC_RELAXED, __HIP_MEMORY_SCOPE_AGENT);
        }
        asm volatile("" ::: "memory");

        // ---- B: psi-core (no halo) while strip loads are in flight ----
        if (pyCore) PSIY_BODY;
        if (pxCore) PSIX_BODY;

        // ---- C: commit imported halo ----
        if (t > 0 && impNb >= 0) sWF[co+imDst] = hval;
        __syncthreads();                                    // b1

        // ---- D: psi-rim ----
        if (pyRim) PSIY_BODY;
        if (pxRim) PSIX_BODY;
        __syncthreads();                                    // b2

        // ---- E: early interior (quads containing exported strip cells) ----
        if (iEarly) INTERIOR_BODY;
        __syncthreads();                                    // b3

        // ---- F: export+publish (free threads) || late interior (core) ----
        if (isFree) {
            if (t < NT-1) {
                int cn = co ^ WHALF;
                float g0 = (es0 >= 0) ? sWF[cn+es0] : 0.f;
                float g1 = (es1 >= 0) ? sWF[cn+es1] : 0.f;
                int pb = (t&1)*SPITCH;
                if (es0 >= 0)
                    __hip_atomic_store(&strips[pb+eg0], g0, __ATOMIC_RELAXED,
                                       __HIP_MEMORY_SCOPE_AGENT);
                if (es1 >= 0)
                    __hip_atomic_store(&strips[pb+eg1], g1, __ATOMIC_RELAXED,
                                       __HIP_MEMORY_SCOPE_AGENT);
                __builtin_amdgcn_s_waitcnt(0);
                if (iFirstFree) {
                    if (atomicAdd(&expCnt, 1) == 15)
                        __hip_atomic_store(&flags[bid], t+1, __ATOMIC_RELEASE,
                                           __HIP_MEMORY_SCOPE_AGENT);
                }
            }
        } else {
            INTERIOR_BODY;
        }
        __syncthreads();                                    // b4

        // ---- record receivers of this step ----
        if (rofs >= 0) out[rofs + t] = sWF[(co^WHALF) + rIdx];

        co ^= WHALF;
    }
#undef PSIY_BODY
#undef PSIX_BODY
#undef INTERIOR_BODY
}

extern "C" void kernel_launch(void* const* d_in, const int* in_sizes, int n_in,
                              void* d_out, int out_size, void* d_ws, size_t ws_size,
                              hipStream_t stream) {
    const float* v    = (const float*)d_in[0];
    const float* amp  = (const float*)d_in[1];
    const int*   sloc = (const int*)d_in[2];
    const int*   rloc = (const int*)d_in[3];
    float* out = (float*)d_out;

    int*   flags  = (int*)d_ws;
    float* strips = (float*)((char*)d_ws + 1024);

    hipMemsetAsync(flags, 0, 1024, stream);
    kWave<<<256, NTH, 0, stream>>>(v, amp, sloc, rloc, out, flags, strips);
}

// Round 10
// 832.902 us; speedup vs baseline: 1.4192x; 1.4192x over previous
//
#include <hip/hip_runtime.h>

#define NVEL  400
#define PMLW  20
#define NSIDE 440
#define BATCH 4
#define NT    100
#define NREC  100

#define TS 55               // tile side; 8x8 tiles x 4 batches = 256 blocks
#define GT 8
#define WP 68               // wf pitch (16B-aligned quads; float cols 0..62 used)
#define WROWS 63            // wf rows: cell rows -4..58
#define WHALF (WROWS*WP)
#define PYP 56              // psiy pitch: storage rows 0..58 = cell rows -2..56
#define PXP 60              // psix pitch: rows y 0..54, float col j = cell x+2
#define C1f (1.0f/48.0f)
#define C2f (1.0f/192.0f)
#define NTH 1024
#define NSTRIP 880          // 4 edges x 4 x 55
#define SPITCH (256*NSTRIP)

typedef float f4 __attribute__((ext_vector_type(4)));
#define F4(x) (*(f4*)&(x))
#define WIDX(y,x) (((y)+4)*WP + ((x)+4))

__global__ __launch_bounds__(NTH, 1) void kWave(
    const float* __restrict__ v, const float* __restrict__ amp,
    const int* __restrict__ sloc, const int* __restrict__ rloc,
    float* __restrict__ out, int* __restrict__ flags, float* __restrict__ strips)
{
    __shared__ __align__(16) float sWF[2*WHALF];
    __shared__ __align__(16) float sPY[59*PYP];
    __shared__ __align__(16) float sPX[TS*PXP];
    __shared__ float pa_y[63], pb_y[63], pa_x[63], pb_x[63];
    __shared__ float sAmp[NT];

    const int tid = threadIdx.x;
    const int bid = blockIdx.x;
    const int b   = bid >> 6;
    const int tl  = bid & 63;
    const int tyi = tl >> 3, txi = tl & 7;
    const int by0 = tyi*TS, bx0 = txi*TS;
    const int nbN = (tyi > 0)    ? bid - GT : -1;
    const int nbS = (tyi < GT-1) ? bid + GT : -1;
    const int nbW = (txi > 0)    ? bid - 1  : -1;
    const int nbE = (txi < GT-1) ? bid + 1  : -1;

    // ---- zero LDS ----
    for (int i = tid; i < 2*WHALF; i += NTH) sWF[i] = 0.f;
    for (int i = tid; i < 59*PYP; i += NTH) sPY[i] = 0.f;
    for (int i = tid; i < TS*PXP; i += NTH) sPX[i] = 0.f;
    if (tid < 63) {
        const float smax = (float)(3.0*2600.0*6.907755278982137/160.0);
        float gy = (float)(by0 + tid - 4);
        float dy = fmaxf(fminf(fmaxf((20.f-gy)/20.f,0.f),1.f),
                         fminf(fmaxf((gy-419.f)/20.f,0.f),1.f));
        float bby = expf(-smax*dy*dy*0.0008f);
        pb_y[tid] = bby; pa_y[tid] = bby - 1.f;
        float gx = (float)(bx0 + tid - 4);
        float dx = fmaxf(fminf(fmaxf((20.f-gx)/20.f,0.f),1.f),
                         fminf(fmaxf((gx-419.f)/20.f,0.f),1.f));
        float bbx = expf(-smax*dx*dx*0.0008f);
        pb_x[tid] = bbx; pa_x[tid] = bbx - 1.f;
    }
    if (tid < NT) sAmp[tid] = amp[b*NT + tid];
    __syncthreads();

    // ============ loop-invariant descriptors (all registers) ============
    // psiy: storage row ri=tid/14 (cell row ri-2), quad col x=(tid%14)*4
    const bool pyOn = (tid < 826);
    const int  pyRi = tid/14, pyQx = (tid - 14*pyRi)*4;
    const bool pyCore = pyOn && (pyRi >= 4 && pyRi <= 54);
    const bool pyRim  = pyOn && !(pyRi >= 4 && pyRi <= 54);
    const int  pyWf  = pyRi*WP + (pyQx+4);
    const int  pyIdx = pyRi*PYP + pyQx;
    float pyPa = 0.f, pyPb = 0.f;
    if (pyOn) { int g = by0 + pyRi - 2;
        if (g >= 0 && g < NSIDE) { pyPa = pa_y[pyRi+2]; pyPb = pb_y[pyRi+2]; } }

    // psix: row y=tid/15, quad j=(tid%15)*4 (cell x = j-2+e)
    const bool pxOn = (tid < 825);
    const int  pxY = tid/15, pxQ = tid - 15*pxY, pxJ = pxQ*4;
    const bool pxCore = pxOn && (pxQ >= 1 && pxQ <= 12);
    const bool pxRim  = pxOn && !(pxQ >= 1 && pxQ <= 12);
    const int  pxWf  = (pxY+4)*WP + pxJ;
    const int  pxIdx = pxY*PXP + pxJ;
    f4 pxPa, pxPb;
    pxPa.x=0.f;pxPa.y=0.f;pxPa.z=0.f;pxPa.w=0.f;
    pxPb.x=0.f;pxPb.y=0.f;pxPb.z=0.f;pxPb.w=0.f;
    if (pxOn) {
        int g0 = bx0 + pxJ - 2;
        if (g0+0 >= 0 && g0+0 < NSIDE) { pxPa.x = pa_x[pxJ+2]; pxPb.x = pb_x[pxJ+2]; }
        if (g0+1 >= 0 && g0+1 < NSIDE) { pxPa.y = pa_x[pxJ+3]; pxPb.y = pb_x[pxJ+3]; }
        if (g0+2 >= 0 && g0+2 < NSIDE) { pxPa.z = pa_x[pxJ+4]; pxPb.z = pb_x[pxJ+4]; }
        if (g0+3 >= 0 && g0+3 < NSIDE) { pxPa.w = pa_x[pxJ+5]; pxPb.w = pb_x[pxJ+5]; }
    }

    // interior: row y=tid/14, quad x=(tid%14)*4; quad 13 = cells 52..54 (+pad)
    const bool inOn = (tid < 770);
    const int  iY = tid/14, iQ = tid - 14*iY, iQx = iQ*4;
    const bool iTail = (iQ == 13);
    const int  iC  = WIDX(iY, iQx);
    const int  iPy = iY*PYP + iQx;
    const int  iPx = iY*PXP + iQx;
    const float iPay = pa_y[iY+4], iPby = pb_y[iY+4];
    f4 iPax, iPbx, iV2, iSrc;
    {
        iPax.x = pa_x[iQx+4]; iPax.y = pa_x[iQx+5]; iPax.z = pa_x[iQx+6]; iPax.w = pa_x[iQx+7];
        iPbx.x = pb_x[iQx+4]; iPbx.y = pb_x[iQx+5]; iPbx.z = pb_x[iQx+6]; iPbx.w = pb_x[iQx+7];
        const int sgy = sloc[b*2] + PMLW, sgx = sloc[b*2+1] + PMLW;
        int cy = min(max(by0 + iY - PMLW, 0), NVEL-1);
        #pragma unroll
        for (int e = 0; e < 4; ++e) {
            int cx = min(max(bx0 + iQx + e - PMLW, 0), NVEL-1);
            float vv = v[cy*NVEL + cx];
            float v2 = vv*vv*(float)(0.0008*0.0008);
            float sm = (inOn && (by0+iY == sgy) && (bx0+iQx+e == sgx)) ? v2 : 0.f;
            if (e==0) { iV2.x=v2; iSrc.x=sm; } else if (e==1) { iV2.y=v2; iSrc.y=sm; }
            else if (e==2) { iV2.z=v2; iSrc.z=sm; } else { iV2.w=v2; iSrc.w=sm; }
        }
    }
    f4 zY, zX;
    zY.x=0.f;zY.y=0.f;zY.z=0.f;zY.w=0.f;
    zX.x=0.f;zX.y=0.f;zX.z=0.f;zX.w=0.f;

    // receivers
    int rofs = -1, rIdx = 0;
    if (tid < NREC) {
        int gry = rloc[(b*NREC+tid)*2]   + PMLW;
        int grx = rloc[(b*NREC+tid)*2+1] + PMLW;
        if (gry >= by0 && gry < by0+TS && grx >= bx0 && grx < bx0+TS) {
            rofs = (b*NREC+tid)*NT;
            rIdx = WIDX(gry-by0, grx-bx0);
        }
    }

    // import descriptors (tid<880):
    // e0: halo rows -4..-1 <- nbN slot1; e1: rows 55..58 <- nbS slot0;
    // e2: cols -4..-1 <- nbW slot3; e3: cols 55..58 <- nbE slot2.
    int impNb = -1, imSrc = 0, imDst = 0;
    // export (tid<880): slot0=rows0..3, slot1=rows51..54 (c-fast),
    //                   slot2=cols0..3, slot3=cols51..54 (r-fast).
    int exSrc = 0;
    if (tid < NSTRIP) {
        int e = tid/220, j = tid - e*220;
        if (e == 0)      { int r=j/55, c=j-55*r; impNb=nbN; imSrc=1*220+j; imDst=WIDX(r-4,c);  exSrc=WIDX(r,c); }
        else if (e == 1) { int r=j/55, c=j-55*r; impNb=nbS; imSrc=0*220+j; imDst=WIDX(55+r,c); exSrc=WIDX(51+r,c); }
        else if (e == 2) { int r=j&3,  c=j>>2;   impNb=nbW; imSrc=3*220+j; imDst=WIDX(c,r-4);  exSrc=WIDX(c,r); }
        else             { int r=j&3,  c=j>>2;   impNb=nbE; imSrc=2*220+j; imDst=WIDX(c,55+r); exSrc=WIDX(c,51+r); }
        if (impNb >= 0) imSrc += impNb*NSTRIP;
    }
    __syncthreads();

    int co = 0;   // cur = sWF+co; nxt = sWF+(co^WHALF)

#define PSIY_BODY { \
    f4 r0 = F4(sWF[co+pyWf]);      f4 r1 = F4(sWF[co+pyWf+WP]); \
    f4 r3 = F4(sWF[co+pyWf+3*WP]); f4 r4 = F4(sWF[co+pyWf+4*WP]); \
    f4 po = F4(sPY[pyIdx]); f4 nv; \
    nv.x = pyPb*po.x + pyPa*((r0.x - r4.x + 8.f*(r3.x - r1.x))*C1f); \
    nv.y = pyPb*po.y + pyPa*((r0.y - r4.y + 8.f*(r3.y - r1.y))*C1f); \
    nv.z = pyPb*po.z + pyPa*((r0.z - r4.z + 8.f*(r3.z - r1.z))*C1f); \
    nv.w = pyPb*po.w + pyPa*((r0.w - r4.w + 8.f*(r3.w - r1.w))*C1f); \
    F4(sPY[pyIdx]) = nv; }

#define PSIX_BODY { \
    f4 L = F4(sWF[co+pxWf]); f4 R = F4(sWF[co+pxWf+4]); \
    f4 po = F4(sPX[pxIdx]); f4 nv; \
    nv.x = pxPb.x*po.x + pxPa.x*((L.x - R.x + 8.f*(L.w - L.y))*C1f); \
    nv.y = pxPb.y*po.y + pxPa.y*((L.y - R.y + 8.f*(R.x - L.z))*C1f); \
    nv.z = pxPb.z*po.z + pxPa.z*((L.z - R.z + 8.f*(R.y - L.w))*C1f); \
    nv.w = pxPb.w*po.w + pxPa.w*((L.w - R.w + 8.f*(R.z - R.x))*C1f); \
    F4(sPX[pxIdx]) = nv; }

    for (int t = 0; t < NT; ++t) {
        // ---- A: poll neighbor flags, issue strip loads ----
        float hval = 0.f;
        if (t > 0 && impNb >= 0) {
            int spin = 0;
            while (__hip_atomic_load(&flags[impNb], __ATOMIC_RELAXED,
                                     __HIP_MEMORY_SCOPE_AGENT) < t
                   && spin < 2000000) { __builtin_amdgcn_s_sleep(1); ++spin; }
            hval = __hip_atomic_load(&strips[((t-1)&1)*SPITCH + imSrc],
                                     __ATOMIC_RELAXED, __HIP_MEMORY_SCOPE_AGENT);
        }
        asm volatile("" ::: "memory");   // keep load issue above psi-core

        // ---- B: psi-core (owned wf only) while strip loads in flight ----
        if (pyCore) PSIY_BODY;
        if (pxCore) PSIX_BODY;

        // ---- C: commit imported halo ----
        if (t > 0 && impNb >= 0) sWF[co+imDst] = hval;
        __syncthreads();                                    // b1

        // ---- D: psi-rim (needs halo) ----
        if (pyRim) PSIY_BODY;
        if (pxRim) PSIX_BODY;
        __syncthreads();                                    // b2

        // ---- E: interior (f4, zeta in registers) ----
        if (inOn) {
            const int cn = co ^ WHALF;
            f4 Cc  = F4(sWF[co+iC]);
            f4 ym2 = F4(sWF[co+iC-2*WP]), ym1 = F4(sWF[co+iC-WP]);
            f4 yp1 = F4(sWF[co+iC+WP]),   yp2 = F4(sWF[co+iC+2*WP]);
            f4 xl  = F4(sWF[co+iC-4]),    xr  = F4(sWF[co+iC+4]);
            f4 p0 = F4(sPY[iPy]),         p1 = F4(sPY[iPy+PYP]);
            f4 p3 = F4(sPY[iPy+3*PYP]),   p4 = F4(sPY[iPy+4*PYP]);
            f4 pl = F4(sPX[iPx]),         pr = F4(sPX[iPx+4]);
            f4 n4 = F4(sWF[cn+iC]);
            const float ampT = sAmp[t];

            float d2y, d2x, w0, w1, w2, w3;
            // e0 (cell x = iQx): xm2=xl.z xm1=xl.w xp1=Cc.y xp2=Cc.z
            d2y = (-(ym2.x+yp2.x) + 16.f*(ym1.x+yp1.x) - 30.f*Cc.x)*C2f
                + (p0.x - p4.x + 8.f*(p3.x - p1.x))*C1f;
            d2x = (-(xl.z + Cc.z) + 16.f*(xl.w + Cc.y) - 30.f*Cc.x)*C2f
                + (pl.x - pr.x + 8.f*(pl.w - pl.y))*C1f;
            zY.x = iPby*zY.x + iPay*d2y;
            zX.x = iPbx.x*zX.x + iPax.x*d2x;
            w0 = iV2.x*(d2y + zY.x + d2x + zX.x) + 2.f*Cc.x - n4.x + iSrc.x*ampT;
            // e1: xm2=xl.w xm1=Cc.x xp1=Cc.z xp2=Cc.w
            d2y = (-(ym2.y+yp2.y) + 16.f*(ym1.y+yp1.y) - 30.f*Cc.y)*C2f
                + (p0.y - p4.y + 8.f*(p3.y - p1.y))*C1f;
            d2x = (-(xl.w + Cc.w) + 16.f*(Cc.x + Cc.z) - 30.f*Cc.y)*C2f
                + (pl.y - pr.y + 8.f*(pr.x - pl.z))*C1f;
            zY.y = iPby*zY.y + iPay*d2y;
            zX.y = iPbx.y*zX.y + iPax.y*d2x;
            w1 = iV2.y*(d2y + zY.y + d2x + zX.y) + 2.f*Cc.y - n4.y + iSrc.y*ampT;
            // e2: xm2=Cc.x xm1=Cc.y xp1=Cc.w xp2=xr.x
            d2y = (-(ym2.z+yp2.z) + 16.f*(ym1.z+yp1.z) - 30.f*Cc.z)*C2f
                + (p0.z - p4.z + 8.f*(p3.z - p1.z))*C1f;
            d2x = (-(Cc.x + xr.x) + 16.f*(Cc.y + Cc.w) - 30.f*Cc.z)*C2f
                + (pl.z - pr.z + 8.f*(pr.y - pl.w))*C1f;
            zY.z = iPby*zY.z + iPay*d2y;
            zX.z = iPbx.z*zX.z + iPax.z*d2x;
            w2 = iV2.z*(d2y + zY.z + d2x + zX.z) + 2.f*Cc.z - n4.z + iSrc.z*ampT;
            // e3: xm2=Cc.y xm1=Cc.z xp1=xr.x xp2=xr.y
            d2y = (-(ym2.w+yp2.w) + 16.f*(ym1.w+yp1.w) - 30.f*Cc.w)*C2f
                + (p0.w - p4.w + 8.f*(p3.w - p1.w))*C1f;
            d2x = (-(Cc.y + xr.y) + 16.f*(Cc.z + xr.x) - 30.f*Cc.w)*C2f
                + (pl.w - pr.w + 8.f*(pr.z - pr.x))*C1f;
            zY.w = iPby*zY.w + iPay*d2y;
            zX.w = iPbx.w*zX.w + iPax.w*d2x;
            w3 = iV2.w*(d2y + zY.w + d2x + zX.w) + 2.f*Cc.w - n4.w + iSrc.w*ampT;

            if (!iTail) {
                f4 w4; w4.x = w0; w4.y = w1; w4.z = w2; w4.w = w3;
                F4(sWF[cn+iC]) = w4;
            } else {
                sWF[cn+iC] = w0; sWF[cn+iC+1] = w1; sWF[cn+iC+2] = w2;
            }
        }
        __syncthreads();                                    // b3

        // ---- F: record + export (coalesced) ----
        const int cn = co ^ WHALF;
        if (rofs >= 0) out[rofs + t] = sWF[cn + rIdx];
        if (t < NT-1 && tid < NSTRIP) {
            __hip_atomic_store(&strips[(t&1)*SPITCH + bid*NSTRIP + tid],
                               sWF[cn + exSrc], __ATOMIC_RELAXED,
                               __HIP_MEMORY_SCOPE_AGENT);
        }
        __builtin_amdgcn_s_waitcnt(0);
        __syncthreads();                                    // b4
        if (t < NT-1 && tid == 0)
            __hip_atomic_store(&flags[bid], t+1, __ATOMIC_RELEASE,
                               __HIP_MEMORY_SCOPE_AGENT);

        co ^= WHALF;
    }
#undef PSIY_BODY
#undef PSIX_BODY
}

extern "C" void kernel_launch(void* const* d_in, const int* in_sizes, int n_in,
                              void* d_out, int out_size, void* d_ws, size_t ws_size,
                              hipStream_t stream) {
    const float* v    = (const float*)d_in[0];
    const float* amp  = (const float*)d_in[1];
    const int*   sloc = (const int*)d_in[2];
    const int*   rloc = (const int*)d_in[3];
    float* out = (float*)d_out;

    int*   flags  = (int*)d_ws;
    float* strips = (float*)((char*)d_ws + 1024);

    hipMemsetAsync(flags, 0, 1024, stream);
    kWave<<<256, NTH, 0, stream>>>(v, amp, sloc, rloc, out, flags, strips);
}